// Round 10
// baseline (3863.398 us; speedup 1.0000x reference)
//
#include <hip/hip_runtime.h>

typedef __attribute__((ext_vector_type(8))) short short8;
typedef __attribute__((ext_vector_type(4))) float f32x4;
typedef __attribute__((ext_vector_type(4))) int   i32x4;

#define MFMA(a,b,c)  __builtin_amdgcn_mfma_f32_16x16x32_bf16(a,b,c,0,0,0)
#define MFMAI(a,b,c) __builtin_amdgcn_mfma_i32_16x16x64_i8(a,b,c,0,0,0)

// Problem dims
#define S_LEN 128
#define IN_D  8
#define HID   512
#define NL    3
#define H8STR 528       // i8 h row stride (bytes)

// ws layout (bytes)
#define OFF_WI8  0                       // [3][32nt][8kk][3g][64][16B] i8 = 2,359,296
#define OFF_WIH  (2359296)               // [3][32][3][64][8] bf16        =   294,912
#define OFF_SW   (2359296 + 294912)      // 4608 f32 dequant scales       =    18,432
#define OFF_SWI  (OFF_SW + 18432)        // 4608 f32 inv scales           =    18,432
#define OFF_FLAG (OFF_SWI + 18432)       // 256 int                       =     1,024
#define OFF_XCHG (OFF_FLAG + 1024)       // 256 blk * 2 slot * 8 KB       = 4,194,304

__device__ __forceinline__ unsigned short f2bf(float f){
  unsigned u = __float_as_uint(f);
  u += 0x7FFFu + ((u >> 16) & 1u);
  return (unsigned short)(u >> 16);
}

// Per-row absmax scales for Whh: row = l*1536 + g*512 + col (4608 rows x 512)
__global__ void prep_scale(const float* __restrict__ Whh,
                           float* __restrict__ sw, float* __restrict__ swi){
  int row = blockIdx.x * 4 + (threadIdx.x >> 6);
  int lane = threadIdx.x & 63;
  const float* src = Whh + (size_t)row * 512;
  float m = 0.f;
#pragma unroll
  for (int i = 0; i < 8; ++i) m = fmaxf(m, fabsf(src[lane + i * 64]));
#pragma unroll
  for (int off = 32; off; off >>= 1) m = fmaxf(m, (float)__shfl_xor(m, off));
  m = fmaxf(m, 1e-20f);
  if (lane == 0){ sw[row] = m / 127.f; swi[row] = 127.f / m; }
}

// Quantize+pack Whh -> i8 B-fragments (K=64), gate-interleaved per kk:
// chunk gid = (((l*32+nt)*8+kk)*3+g)*64+lane, 16 bytes: byte j =
//   q(Whh[l][g*512+nt*16+(lane&15)][kk*64+(lane>>4)*16+j])
__global__ void prep_wi8(const float* __restrict__ Whh, const float* __restrict__ swi,
                         unsigned char* __restrict__ Wp8){
  int gid = blockIdx.x * 256 + threadIdx.x;     // 147456 total
  int lane = gid & 63;
  int r = gid >> 6;
  int g  = r % 3;  r /= 3;
  int kk = r & 7;  r >>= 3;
  int nt = r & 31;
  int l  = r >> 5;
  int row = l * 1536 + g * 512 + nt * 16 + (lane & 15);
  int k0  = kk * 64 + (lane >> 4) * 16;
  const float* src = Whh + (size_t)row * 512 + k0;
  float si = swi[row];
  uint4 v = {0,0,0,0};
  unsigned w[4] = {0,0,0,0};
#pragma unroll
  for (int j = 0; j < 16; ++j){
    int q = (int)rintf(src[j] * si);
    q = q > 127 ? 127 : (q < -127 ? -127 : q);
    w[j >> 2] |= ((unsigned)(q & 0xFF)) << ((j & 3) * 8);
  }
  v.x = w[0]; v.y = w[1]; v.z = w[2]; v.w = w[3];
  *(uint4*)(Wp8 + (size_t)gid * 16) = v;
}

// Pack Wih [3][1536][8] -> zero-padded (K=8 of 32) bf16 B-fragments, gate-interleaved
__global__ void prep_wih(const float* __restrict__ Wih, unsigned short* __restrict__ Wip){
  int gid = blockIdx.x * 256 + threadIdx.x;     // 18432 total
  int lane = gid & 63;
  int r = gid >> 6;
  int g  = r % 3;  r /= 3;
  int nt = r & 31;
  int l  = r >> 5;
  unsigned short t[8] = {0,0,0,0,0,0,0,0};
  if ((lane >> 4) == 0){
    int n = g * 512 + nt * 16 + (lane & 15);
    const float* src = Wih + ((size_t)l * 1536 + n) * 8;
#pragma unroll
    for (int j = 0; j < 8; ++j) t[j] = f2bf(src[j]);
  }
  uint4 v;
  v.x = t[0] | ((unsigned)t[1] << 16);
  v.y = t[2] | ((unsigned)t[3] << 16);
  v.z = t[4] | ((unsigned)t[5] << 16);
  v.w = t[6] | ((unsigned)t[7] << 16);
  *(uint4*)(Wip + (size_t)gid * 8) = v;
}

// Main: 256 blocks x 512 threads (8 waves, 2/SIMD), 1 block/CU (LDS 82,944 B).
// Pair (bid, bid^4) shares batch rows [b0,b0+32); each computes 256 of 512 cols.
// Wave owns 32 cols (2 ntiles) -> A-frags reused x2, 6 KB weight loads in flight/kk,
// and a 256-VGPR budget (8-wave block) so the compiler can actually pipeline.
__global__ __launch_bounds__(512, 2) void gru_main(
    const float* __restrict__ x,
    const unsigned char* __restrict__ Wp8,
    const unsigned short* __restrict__ Wip,
    const float* __restrict__ bih,
    const float* __restrict__ bhh,
    const float* __restrict__ sw,
    float* __restrict__ out,
    int* __restrict__ flags,
    unsigned int* __restrict__ xchg)
{
  __shared__ __align__(16) unsigned char  hB8[2][32 * H8STR]; // 33,792 B
  __shared__ __align__(16) unsigned short xpack[2][1024];     //  4,096 B
  __shared__ float sBrz[3 * 1024];                            // 12,288 B
  __shared__ float sBni[3 * 512];                             //  6,144 B
  __shared__ float sBnh[3 * 512];                             //  6,144 B
  __shared__ float sSw[4608];                                 // 18,432 B
  __shared__ int   pad[512];                                  //  2,048 B -> 82,944 total

  const int tid  = threadIdx.x;
  const int wv   = tid >> 6;          // 0..7
  const int lane = tid & 63;
  const int l15  = lane & 15;
  const int l4   = lane >> 4;

  const int bid     = blockIdx.x;
  const int bgroup  = ((bid >> 3) << 2) | (bid & 3);   // [0,128)
  const int half    = (bid >> 2) & 1;
  const int partner = bid ^ 4;
  const int b0      = bgroup * 32;
  const int col     = half * 256 + wv * 32 + l15;      // ntile0 global col
  const int ntc0    = half * 16 + wv * 2;              // first 16-col tile
  const int pcb0    = (1 - half) * 256;                // partner col base (bytes)
  const int ko0     = half * 4;                        // own-half kk start
  const int pk0     = 4 - ko0;                         // partner-half kk start

  // pad liveness guard (flags never negative) — prevents LDS DCE (R8 lesson)
  if (flags[bid] == -1) pad[tid] = tid;

  unsigned int* xown = xchg + (size_t)bid * 4096;      // 2 slots x 2048 u32
  const unsigned int* xpb = xchg + (size_t)partner * 4096 + tid;
  const int dOff0 = (tid >> 6) * H8STR + pcb0 + (tid & 63) * 4;  // +k*8*H8STR

  for (int i = tid; i < 2 * 32 * H8STR / 4; i += 512) ((unsigned*)hB8)[i] = 0;
  for (int i = tid; i < 3072; i += 512){
    int l = i >> 10, c = i & 1023;
    sBrz[i] = bih[l * 1536 + c] + bhh[l * 1536 + c];
  }
  for (int i = tid; i < 1536; i += 512){
    int l = i >> 9, c = i & 511;
    sBni[i] = bih[l * 1536 + 1024 + c];
    sBnh[i] = bhh[l * 1536 + 1024 + c];
  }
  for (int i = tid; i < 4608; i += 512) sSw[i] = sw[i];

  float hreg[2][2][4];      // [nt][m][q]
#pragma unroll
  for (int nt = 0; nt < 2; ++nt)
#pragma unroll
    for (int m = 0; m < 2; ++m)
#pragma unroll
      for (int q = 0; q < 4; ++q) hreg[nt][m][q] = 0.f;

  // xpack writer: entry idx = (m*64+lane)*8+j ; this thread covers idx=tid (m=0) and tid+512 (m=1)
  const int xl = (tid >> 3) & 63;
  const size_t xbase  = ((size_t)(b0 + (xl & 15))) * (S_LEN * IN_D) + (tid & 7);
  const size_t xbase2 = xbase + (size_t)16 * (S_LEN * IN_D);
  const int xvalid = (xl < 16);
  {
    xpack[0][tid]       = f2bf(xvalid ? x[xbase]  : 0.f);
    xpack[0][tid + 512] = f2bf(xvalid ? x[xbase2] : 0.f);
  }
  __syncthreads();

  const int aoff0 = l15 * H8STR + l4 * 16;        // A-frag m=0 (rows 0..15), bytes
  const int aoff1 = aoff0 + 16 * H8STR;           // A-frag m=1

  const unsigned char*  wkl0B = Wp8 + (size_t)ntc0 * 24576 + (size_t)lane * 16;
  const unsigned short* wil0B = Wip + (size_t)ntc0 * 1536 + (size_t)lane * 8;
  const float i127 = 1.f / 127.f;

#define DO_KK(kkv) { \
    const int kk_ = (kkv); \
    const unsigned char* w0_ = wkl0 + kk_ * 3072; \
    const unsigned char* w1_ = wkl1 + kk_ * 3072; \
    i32x4 bR0 = *(const i32x4*)(w0_); \
    i32x4 bZ0 = *(const i32x4*)(w0_ + 1024); \
    i32x4 bN0 = *(const i32x4*)(w0_ + 2048); \
    i32x4 bR1 = *(const i32x4*)(w1_); \
    i32x4 bZ1 = *(const i32x4*)(w1_ + 1024); \
    i32x4 bN1 = *(const i32x4*)(w1_ + 2048); \
    i32x4 a0 = *(const i32x4*)(hb8c + aoff0 + kk_ * 64); \
    i32x4 a1 = *(const i32x4*)(hb8c + aoff1 + kk_ * 64); \
    aR[0][0] = MFMAI(a0, bR0, aR[0][0]);  aR[0][1] = MFMAI(a1, bR0, aR[0][1]); \
    aZ[0][0] = MFMAI(a0, bZ0, aZ[0][0]);  aZ[0][1] = MFMAI(a1, bZ0, aZ[0][1]); \
    aN[0][0] = MFMAI(a0, bN0, aN[0][0]);  aN[0][1] = MFMAI(a1, bN0, aN[0][1]); \
    aR[1][0] = MFMAI(a0, bR1, aR[1][0]);  aR[1][1] = MFMAI(a1, bR1, aR[1][1]); \
    aZ[1][0] = MFMAI(a0, bZ1, aZ[1][0]);  aZ[1][1] = MFMAI(a1, bZ1, aZ[1][1]); \
    aN[1][0] = MFMAI(a0, bN1, aN[1][0]);  aN[1][1] = MFMAI(a1, bN1, aN[1][1]); \
  }

  int cur = 0;
#pragma unroll 1
  for (int t = 0; t < S_LEN; ++t){
    const unsigned short* xp = &xpack[t & 1][0];
#pragma unroll 1
    for (int l = 0; l < NL; ++l){
      const int s    = t * NL + l;
      const int last = (s == S_LEN * NL - 1);
      const unsigned char* hb8c = hB8[cur];
      unsigned char*       hb8w = hB8[cur];
      unsigned char*       hb8n = hB8[cur ^ 1];
      const unsigned char*  wkl0 = wkl0B + (size_t)l * 786432;
      const unsigned char*  wkl1 = wkl0 + 24576;
      const unsigned short* wil  = wil0B + (size_t)l * 49152;

      // poll partner + issue 4 mailbox u32 loads; LDS writes deferred to mid-barrier
      unsigned c0 = 0, c1 = 0, c2 = 0, c3 = 0;
      if (s > 0){
        while (__hip_atomic_load(&flags[partner], __ATOMIC_RELAXED, __HIP_MEMORY_SCOPE_AGENT) < s)
          __builtin_amdgcn_s_sleep(4);
        const unsigned int* src = xpb + ((s - 1) & 1) * 2048;
        c0 = __hip_atomic_load(src,        __ATOMIC_RELAXED, __HIP_MEMORY_SCOPE_AGENT);
        c1 = __hip_atomic_load(src + 512,  __ATOMIC_RELAXED, __HIP_MEMORY_SCOPE_AGENT);
        c2 = __hip_atomic_load(src + 1024, __ATOMIC_RELAXED, __HIP_MEMORY_SCOPE_AGENT);
        c3 = __hip_atomic_load(src + 1536, __ATOMIC_RELAXED, __HIP_MEMORY_SCOPE_AGENT);
      }

      // biases + gi accumulators
      const float vR0  = sBrz[l * 1024 + col],        vR1  = sBrz[l * 1024 + col + 16];
      const float vZ0  = sBrz[l * 1024 + 512 + col],  vZ1  = sBrz[l * 1024 + 512 + col + 16];
      const float vNi0 = sBni[l * 512 + col],         vNi1 = sBni[l * 512 + col + 16];
      const float vNh0 = sBnh[l * 512 + col],         vNh1 = sBnh[l * 512 + col + 16];
      f32x4 gR[2][2], gZ[2][2], gN[2][2];
#pragma unroll
      for (int m = 0; m < 2; ++m){
        gR[0][m] = (f32x4){vR0,vR0,vR0,vR0};   gR[1][m] = (f32x4){vR1,vR1,vR1,vR1};
        gZ[0][m] = (f32x4){vZ0,vZ0,vZ0,vZ0};   gZ[1][m] = (f32x4){vZ1,vZ1,vZ1,vZ1};
        gN[0][m] = (f32x4){vNi0,vNi0,vNi0,vNi0}; gN[1][m] = (f32x4){vNi1,vNi1,vNi1,vNi1};
      }

      // gi = x_t @ Wih^T (bf16, zero-padded K=8)
      {
        short8 ax0 = *(const short8*)(xp + lane * 8);
        short8 ax1 = *(const short8*)(xp + 512 + lane * 8);
        short8 i0R = *(const short8*)(wil);
        short8 i0Z = *(const short8*)(wil + 512);
        short8 i0N = *(const short8*)(wil + 1024);
        short8 i1R = *(const short8*)(wil + 1536);
        short8 i1Z = *(const short8*)(wil + 2048);
        short8 i1N = *(const short8*)(wil + 2560);
        gR[0][0] = MFMA(ax0, i0R, gR[0][0]);  gR[0][1] = MFMA(ax1, i0R, gR[0][1]);
        gZ[0][0] = MFMA(ax0, i0Z, gZ[0][0]);  gZ[0][1] = MFMA(ax1, i0Z, gZ[0][1]);
        gN[0][0] = MFMA(ax0, i0N, gN[0][0]);  gN[0][1] = MFMA(ax1, i0N, gN[0][1]);
        gR[1][0] = MFMA(ax0, i1R, gR[1][0]);  gR[1][1] = MFMA(ax1, i1R, gR[1][1]);
        gZ[1][0] = MFMA(ax0, i1Z, gZ[1][0]);  gZ[1][1] = MFMA(ax1, i1Z, gZ[1][1]);
        gN[1][0] = MFMA(ax0, i1N, gN[1][0]);  gN[1][1] = MFMA(ax1, i1N, gN[1][1]);
      }

      i32x4 aR[2][2], aZ[2][2], aN[2][2];
#pragma unroll
      for (int nt = 0; nt < 2; ++nt)
#pragma unroll
        for (int m = 0; m < 2; ++m){
          aR[nt][m] = (i32x4){0,0,0,0};
          aZ[nt][m] = (i32x4){0,0,0,0};
          aN[nt][m] = (i32x4){0,0,0,0};
        }

      // own-half kks
#pragma unroll
      for (int kx = 0; kx < 4; ++kx) DO_KK(ko0 + kx);

      // partner-copy LDS writes + mid-barrier
      if (s > 0){
        *(unsigned*)(hb8w + dOff0)                = c0;
        *(unsigned*)(hb8w + dOff0 + 8  * H8STR)   = c1;
        *(unsigned*)(hb8w + dOff0 + 16 * H8STR)   = c2;
        *(unsigned*)(hb8w + dOff0 + 24 * H8STR)   = c3;
      }
      __syncthreads();

      // partner-half kks
#pragma unroll
      for (int kx = 0; kx < 4; ++kx) DO_KK(pk0 + kx);

      // gates: dequant, fp32 nonlinearity, h write i8 (LDS + mailbox)
      const float kR0 = sSw[l * 1536 + col] * i127,        kR1 = sSw[l * 1536 + col + 16] * i127;
      const float kZ0 = sSw[l * 1536 + 512 + col] * i127,  kZ1 = sSw[l * 1536 + 512 + col + 16] * i127;
      const float kN0 = sSw[l * 1536 + 1024 + col] * i127, kN1 = sSw[l * 1536 + 1024 + col + 16] * i127;
      unsigned int* xob = xown + (s & 1) * 2048;
#pragma unroll
      for (int nt = 0; nt < 2; ++nt){
        const float kR = nt ? kR1 : kR0;
        const float kZ = nt ? kZ1 : kZ0;
        const float kN = nt ? kN1 : kN0;
        const float vNh = nt ? vNh1 : vNh0;
#pragma unroll
        for (int m = 0; m < 2; ++m){
#pragma unroll
          for (int q = 0; q < 4; ++q){
            int b = m * 16 + l4 * 4 + q;
            float rpre = gR[nt][m][q] + (float)aR[nt][m][q] * kR;
            float zpre = gZ[nt][m][q] + (float)aZ[nt][m][q] * kZ;
            float r  = 1.f / (1.f + __expf(-rpre));
            float z  = 1.f / (1.f + __expf(-zpre));
            float an = gN[nt][m][q] + r * ((float)aN[nt][m][q] * kN + vNh);
            float n  = 1.f - 2.f / (1.f + __expf(2.f * an));
            float hn = n + z * (hreg[nt][m][q] - n);
            hreg[nt][m][q] = hn;
            int hq = (int)rintf(hn * 127.f);
            unsigned b8  = (unsigned)(hq & 0xFF);
            unsigned p1  = (unsigned)__shfl_xor((int)b8, 1);
            unsigned h16 = b8 | (p1 << 8);
            unsigned p2  = (unsigned)__shfl_xor((int)h16, 2);
            unsigned w32 = (h16 & 0xFFFF) | (p2 << 16);
            if (!(l15 & 3)){
              *(unsigned*)(hb8n + b * H8STR + col + nt * 16) = w32;
              if (!last)
                __hip_atomic_store(xob + b * 64 + wv * 8 + nt * 4 + (l15 >> 2), w32,
                                   __ATOMIC_RELAXED, __HIP_MEMORY_SCOPE_AGENT);
            }
          }
        }
      }

      // stage x(t+1) before the end-of-step barrier
      if (l == NL - 1 && t < S_LEN - 1){
        xpack[(t + 1) & 1][tid]       = f2bf(xvalid ? x[xbase  + (size_t)(t + 1) * IN_D] : 0.f);
        xpack[(t + 1) & 1][tid + 512] = f2bf(xvalid ? x[xbase2 + (size_t)(t + 1) * IN_D] : 0.f);
      }

      if (!last){
        asm volatile("s_waitcnt vmcnt(0)" ::: "memory");   // mailbox stores drained
        __syncthreads();
        if (tid == 0)
          __hip_atomic_store(&flags[bid], s + 1, __ATOMIC_RELAXED, __HIP_MEMORY_SCOPE_AGENT);
      }
      cur ^= 1;
    }
  }
#undef DO_KK

  // epilogue: own 32r x 32c slice from fp32 registers
#pragma unroll
  for (int nt = 0; nt < 2; ++nt)
#pragma unroll
    for (int m = 0; m < 2; ++m)
#pragma unroll
      for (int q = 0; q < 4; ++q){
        int b = m * 16 + l4 * 4 + q;
        out[((size_t)(b0 + b)) * 512 + col + nt * 16] = hreg[nt][m][q];
      }

  if (flags[bid] == -2) out[0] = (float)pad[tid];   // pad liveness (never true)
}

extern "C" void kernel_launch(void* const* d_in, const int* in_sizes, int n_in,
                              void* d_out, int out_size, void* d_ws, size_t ws_size,
                              hipStream_t stream){
  const float* x   = (const float*)d_in[0];
  const float* Wih = (const float*)d_in[1];
  const float* Whh = (const float*)d_in[2];
  const float* bih = (const float*)d_in[3];
  const float* bhh = (const float*)d_in[4];

  unsigned char* ws = (unsigned char*)d_ws;
  unsigned char*  Wp8  = (unsigned char*)(ws + OFF_WI8);
  unsigned short* Wip  = (unsigned short*)(ws + OFF_WIH);
  float*          sw   = (float*)(ws + OFF_SW);
  float*          swi  = (float*)(ws + OFF_SWI);
  int*            flg  = (int*)(ws + OFF_FLAG);
  unsigned int*   xchg = (unsigned int*)(ws + OFF_XCHG);

  hipMemsetAsync(flg, 0, 256 * sizeof(int), stream);
  prep_scale<<<1152, 256, 0, stream>>>(Whh, sw, swi);
  prep_wi8  <<< 576, 256, 0, stream>>>(Whh, swi, Wp8);
  prep_wih  <<<  72, 256, 0, stream>>>(Wih, Wip);
  gru_main  <<< 256, 512, 0, stream>>>(x, Wp8, Wip, bih, bhh, sw, (float*)d_out, flg, xchg);
}

// Round 11
// 2837.104 us; speedup vs baseline: 1.3617x; 1.3617x over previous
//
#include <hip/hip_runtime.h>

typedef __attribute__((ext_vector_type(8))) short short8;
typedef __attribute__((ext_vector_type(4))) float f32x4;
typedef __attribute__((ext_vector_type(4))) int   i32x4;

#define MFMA(a,b,c)  __builtin_amdgcn_mfma_f32_16x16x32_bf16(a,b,c,0,0,0)
#define MFMAI(a,b,c) __builtin_amdgcn_mfma_i32_16x16x64_i8(a,b,c,0,0,0)

// Problem dims
#define S_LEN 128
#define IN_D  8
#define HID   512
#define NL    3
#define H8STR 528       // i8 h row stride (bytes)
#define LOG2E  1.4426950408889634f
#define LOG2E2 2.8853901617779268f   // 2*log2e

// ws layout (bytes)
#define OFF_WI8  0                       // [3][32nt][8kk][3g][64][16B] i8 = 2,359,296
#define OFF_WIH  (2359296)               // [3][32][3][64][8] bf16        =   294,912
#define OFF_SW   (2359296 + 294912)      // 4608 f32 dequant scales       =    18,432
#define OFF_SWI  (OFF_SW + 18432)        // 4608 f32 inv scales           =    18,432
#define OFF_FLAG (OFF_SWI + 18432)       // 256 int                       =     1,024
#define OFF_XCHG (OFF_FLAG + 1024)       // 256 blk * 2 slot * 8 KB       = 4,194,304

__device__ __forceinline__ unsigned short f2bf(float f){
  unsigned u = __float_as_uint(f);
  u += 0x7FFFu + ((u >> 16) & 1u);
  return (unsigned short)(u >> 16);
}
__device__ __forceinline__ float fexp2(float x){ return __builtin_amdgcn_exp2f(x); }
__device__ __forceinline__ float frcp(float x){ return __builtin_amdgcn_rcpf(x); }

// Per-row absmax scales for Whh: row = l*1536 + g*512 + col (4608 rows x 512)
__global__ void prep_scale(const float* __restrict__ Whh,
                           float* __restrict__ sw, float* __restrict__ swi){
  int row = blockIdx.x * 4 + (threadIdx.x >> 6);
  int lane = threadIdx.x & 63;
  const float* src = Whh + (size_t)row * 512;
  float m = 0.f;
#pragma unroll
  for (int i = 0; i < 8; ++i) m = fmaxf(m, fabsf(src[lane + i * 64]));
#pragma unroll
  for (int off = 32; off; off >>= 1) m = fmaxf(m, (float)__shfl_xor(m, off));
  m = fmaxf(m, 1e-20f);
  if (lane == 0){ sw[row] = m / 127.f; swi[row] = 127.f / m; }
}

// Quantize+pack Whh -> i8 A-fragments (K=64), gate-interleaved per kk:
// chunk gid = (((l*32+nt)*8+kk)*3+g)*64+lane, byte j =
//   q(Whh[l][g*512+nt*16+(lane&15)][kk*64+(lane>>4)*16+j])   (A-frag: row=lane&15)
__global__ void prep_wi8(const float* __restrict__ Whh, const float* __restrict__ swi,
                         unsigned char* __restrict__ Wp8){
  int gid = blockIdx.x * 256 + threadIdx.x;     // 147456 total
  int lane = gid & 63;
  int r = gid >> 6;
  int g  = r % 3;  r /= 3;
  int kk = r & 7;  r >>= 3;
  int nt = r & 31;
  int l  = r >> 5;
  int row = l * 1536 + g * 512 + nt * 16 + (lane & 15);
  int k0  = kk * 64 + (lane >> 4) * 16;
  const float* src = Whh + (size_t)row * 512 + k0;
  float si = swi[row];
  uint4 v = {0,0,0,0};
  unsigned w[4] = {0,0,0,0};
#pragma unroll
  for (int j = 0; j < 16; ++j){
    int q = (int)rintf(src[j] * si);
    q = q > 127 ? 127 : (q < -127 ? -127 : q);
    w[j >> 2] |= ((unsigned)(q & 0xFF)) << ((j & 3) * 8);
  }
  v.x = w[0]; v.y = w[1]; v.z = w[2]; v.w = w[3];
  *(uint4*)(Wp8 + (size_t)gid * 16) = v;
}

// Pack Wih [3][1536][8] -> zero-padded (K=8 of 32) bf16 A-fragments, gate-interleaved,
// PRESCALED by log2e (r,z) / 2*log2e (n) for exp2-domain gates.
__global__ void prep_wih(const float* __restrict__ Wih, unsigned short* __restrict__ Wip){
  int gid = blockIdx.x * 256 + threadIdx.x;     // 18432 total
  int lane = gid & 63;
  int r = gid >> 6;
  int g  = r % 3;  r /= 3;
  int nt = r & 31;
  int l  = r >> 5;
  float scl = (g == 2) ? LOG2E2 : LOG2E;
  unsigned short t[8] = {0,0,0,0,0,0,0,0};
  if ((lane >> 4) == 0){
    int n = g * 512 + nt * 16 + (lane & 15);
    const float* src = Wih + ((size_t)l * 1536 + n) * 8;
#pragma unroll
    for (int j = 0; j < 8; ++j) t[j] = f2bf(src[j] * scl);
  }
  uint4 v;
  v.x = t[0] | ((unsigned)t[1] << 16);
  v.y = t[2] | ((unsigned)t[3] << 16);
  v.z = t[4] | ((unsigned)t[5] << 16);
  v.w = t[6] | ((unsigned)t[7] << 16);
  *(uint4*)(Wip + (size_t)gid * 8) = v;
}

// Main: 256 blocks x 1024 threads (16 waves), 1 block/CU.
// Pair (bid, bid^4) shares batch rows [b0,b0+32); each computes 256 of 512 cols.
// SWAPPED MFMA roles: A = weights (M=outcols), B = h (N=batch). C/D rows = outcols,
// so each lane owns 4 CONSECUTIVE out-cols -> u32 h-stores, no shfl, no predication.
// Gates in exp2 domain (prescaled weights/biases/scales), native rcp.
__global__ __launch_bounds__(1024) void gru_main(
    const float* __restrict__ x,
    const unsigned char* __restrict__ Wp8,
    const unsigned short* __restrict__ Wip,
    const float* __restrict__ bih,
    const float* __restrict__ bhh,
    const float* __restrict__ sw,
    float* __restrict__ out,
    int* __restrict__ flags,
    unsigned int* __restrict__ xchg)
{
  __shared__ __align__(16) unsigned char  hB8[2][32 * H8STR]; // 33,792 B
  __shared__ __align__(16) unsigned short xpack[2][1024];     //  4,096 B
  __shared__ __align__(16) float sBrz[3 * 1024];              // 12,288 B  (x log2e)
  __shared__ __align__(16) float sBni[3 * 512];               //  6,144 B  (x 2log2e)
  __shared__ __align__(16) float sBnh[3 * 512];               //  6,144 B  (x 2log2e)
  __shared__ __align__(16) float sK[4608];                    // 18,432 B  dequant*log2-domain
  __shared__ int   pad[1024];                                 //  4,096 B -> 84,992 total

  const int tid  = threadIdx.x;
  const int wv   = tid >> 6;
  const int lane = tid & 63;
  const int l15  = lane & 15;
  const int l4   = lane >> 4;

  const int bid     = blockIdx.x;
  const int bgroup  = ((bid >> 3) << 2) | (bid & 3);   // [0,128)
  const int half    = (bid >> 2) & 1;
  const int partner = bid ^ 4;
  const int b0      = bgroup * 32;
  const int colv    = half * 256 + wv * 16 + l4 * 4;   // lane's first out-col (4 consecutive)
  const int ntc     = half * 16 + wv;                  // 16-col tile index
  const int pcb0    = (1 - half) * 256;                // partner col base (bytes)
  const int ko0     = half * 4;                        // own-half kk start
  const int pk0     = 4 - ko0;                         // partner-half kk start

  // pad liveness guard (flags never negative) — prevents LDS DCE (R8 lesson)
  if (flags[bid] == -1) pad[tid] = tid;

  unsigned int* xown = xchg + (size_t)bid * 4096;      // 2 slots x 2048 u32
  const unsigned int* xpb = xchg + (size_t)partner * 4096 + tid;
  const int dOff = (tid >> 6) * H8STR + pcb0 + (tid & 63) * 4;   // +k*8*H8STR

  for (int i = tid; i < 2 * 32 * H8STR / 4; i += 1024) ((unsigned*)hB8)[i] = 0;
  for (int i = tid; i < 3072; i += 1024){
    int l = i >> 10, c = i & 1023;
    sBrz[i] = (bih[l * 1536 + c] + bhh[l * 1536 + c]) * LOG2E;
  }
  for (int i = tid; i < 1536; i += 1024){
    int l = i >> 9, c = i & 511;
    sBni[i] = bih[l * 1536 + 1024 + c] * LOG2E2;
    sBnh[i] = bhh[l * 1536 + 1024 + c] * LOG2E2;
  }
  for (int i = tid; i < 4608; i += 1024){
    int g = (i % 1536) >> 9;
    sK[i] = sw[i] * (1.f / 127.f) * (g == 2 ? LOG2E2 : LOG2E);
  }

  float hreg[2][4];   // [batch-frag][outcol q]
#pragma unroll
  for (int nf = 0; nf < 2; ++nf)
#pragma unroll
    for (int q = 0; q < 4; ++q) hreg[nf][q] = 0.f;

  // xpack writer: entry (m*64+ln)*8+j = x[b0+m*16+(ln&15)][j] for ln<16 else 0
  const int xl = (tid >> 3) & 63;
  const size_t xbase = ((size_t)(b0 + (tid >> 9) * 16 + (xl & 15))) * (S_LEN * IN_D) + (tid & 7);
  const int xvalid = (xl < 16);
  { float xv = xvalid ? x[xbase] : 0.f; xpack[0][tid] = f2bf(xv); }
  __syncthreads();

  const int boff0 = l15 * H8STR + l4 * 16;        // h B-frag nf=0 (batch 0..15), bytes
  const int boff1 = boff0 + 16 * H8STR;           // nf=1 (batch 16..31)

  const unsigned char*  wklB = Wp8 + (size_t)ntc * (8 * 3 * 64 * 16) + (size_t)lane * 16;
  const unsigned short* wilB = Wip + (size_t)ntc * 3 * 512 + (size_t)lane * 8;

#define DO_KK(kkv) { \
    const int kk_ = (kkv); \
    const unsigned char* w_ = wkl + kk_ * 3072; \
    i32x4 wR = *(const i32x4*)(w_); \
    i32x4 wZ = *(const i32x4*)(w_ + 1024); \
    i32x4 wN = *(const i32x4*)(w_ + 2048); \
    i32x4 hb0 = *(const i32x4*)(hb8c + boff0 + kk_ * 64); \
    i32x4 hb1 = *(const i32x4*)(hb8c + boff1 + kk_ * 64); \
    aR[0] = MFMAI(wR, hb0, aR[0]);  aR[1] = MFMAI(wR, hb1, aR[1]); \
    aZ[0] = MFMAI(wZ, hb0, aZ[0]);  aZ[1] = MFMAI(wZ, hb1, aZ[1]); \
    aN[0] = MFMAI(wN, hb0, aN[0]);  aN[1] = MFMAI(wN, hb1, aN[1]); \
  }

  int cur = 0;
#pragma unroll 1
  for (int t = 0; t < S_LEN; ++t){
    const unsigned short* xp = &xpack[t & 1][0];
#pragma unroll 1
    for (int l = 0; l < NL; ++l){
      const int s    = t * NL + l;
      const int last = (s == S_LEN * NL - 1);
      const unsigned char* hb8c = hB8[cur];
      unsigned char*       hb8w = hB8[cur];
      unsigned char*       hb8n = hB8[cur ^ 1];
      const unsigned char*  wkl = wklB + (size_t)l * (32 * 8 * 3 * 64 * 16);
      const unsigned short* wil = wilB + (size_t)l * (32 * 3 * 512);

      // poll partner + issue 2 mailbox u32 loads; LDS writes deferred to mid-barrier
      unsigned c0 = 0, c1 = 0;
      if (s > 0){
        while (__hip_atomic_load(&flags[partner], __ATOMIC_RELAXED, __HIP_MEMORY_SCOPE_AGENT) < s)
          __builtin_amdgcn_s_sleep(4);
        const unsigned int* src = xpb + ((s - 1) & 1) * 2048;
        c0 = __hip_atomic_load(src,        __ATOMIC_RELAXED, __HIP_MEMORY_SCOPE_AGENT);
        c1 = __hip_atomic_load(src + 1024, __ATOMIC_RELAXED, __HIP_MEMORY_SCOPE_AGENT);
      }

      // per-outcol bias/scale vectors: component q == acc component q
      const f32x4 vR4  = *(const f32x4*)&sBrz[l * 1024 + colv];
      const f32x4 vZ4  = *(const f32x4*)&sBrz[l * 1024 + 512 + colv];
      const f32x4 vNi4 = *(const f32x4*)&sBni[l * 512 + colv];
      const f32x4 vNh4 = *(const f32x4*)&sBnh[l * 512 + colv];
      const f32x4 kR4  = *(const f32x4*)&sK[l * 1536 + colv];
      const f32x4 kZ4  = *(const f32x4*)&sK[l * 1536 + 512 + colv];
      const f32x4 kN4  = *(const f32x4*)&sK[l * 1536 + 1024 + colv];

      f32x4 gR[2], gZ[2], gN[2];
      gR[0] = vR4;  gR[1] = vR4;
      gZ[0] = vZ4;  gZ[1] = vZ4;
      gN[0] = vNi4; gN[1] = vNi4;

      // gi = Wih-frag (A) x x-frag (B), bf16 K=8-of-32
      {
        short8 wiR = *(const short8*)(wil);
        short8 wiZ = *(const short8*)(wil + 512);
        short8 wiN = *(const short8*)(wil + 1024);
        short8 xb0 = *(const short8*)(xp + lane * 8);
        short8 xb1 = *(const short8*)(xp + 512 + lane * 8);
        gR[0] = MFMA(wiR, xb0, gR[0]);  gR[1] = MFMA(wiR, xb1, gR[1]);
        gZ[0] = MFMA(wiZ, xb0, gZ[0]);  gZ[1] = MFMA(wiZ, xb1, gZ[1]);
        gN[0] = MFMA(wiN, xb0, gN[0]);  gN[1] = MFMA(wiN, xb1, gN[1]);
      }

      i32x4 aR[2], aZ[2], aN[2];
#pragma unroll
      for (int nf = 0; nf < 2; ++nf){
        aR[nf] = (i32x4){0,0,0,0};
        aZ[nf] = (i32x4){0,0,0,0};
        aN[nf] = (i32x4){0,0,0,0};
      }

      // own-half kks
#pragma unroll
      for (int kx = 0; kx < 4; ++kx) DO_KK(ko0 + kx);

      // partner-copy LDS writes + mid-barrier
      if (s > 0){
        *(unsigned*)(hb8w + dOff)              = c0;
        *(unsigned*)(hb8w + dOff + 16 * H8STR) = c1;
      }
      __syncthreads();

      // partner-half kks
#pragma unroll
      for (int kx = 0; kx < 4; ++kx) DO_KK(pk0 + kx);

      // gates: exp2-domain, native rcp; lane owns (batch = nf*16+l15, outcols colv..+3)
      unsigned int* xob = xown + (s & 1) * 2048;
#pragma unroll
      for (int nf = 0; nf < 2; ++nf){
        unsigned pk = 0;
#pragma unroll
        for (int q = 0; q < 4; ++q){
          float rp = gR[nf][q] + (float)aR[nf][q] * kR4[q];
          float zp = gZ[nf][q] + (float)aZ[nf][q] * kZ4[q];
          float r  = frcp(1.f + fexp2(-rp));
          float z  = frcp(1.f + fexp2(-zp));
          float an = gN[nf][q] + r * ((float)aN[nf][q] * kN4[q] + vNh4[q]);
          float n  = fmaf(-2.f, frcp(1.f + fexp2(an)), 1.f);
          float hn = fmaf(z, hreg[nf][q] - n, n);
          hreg[nf][q] = hn;
          int hq = (int)rintf(hn * 127.f);
          pk |= ((unsigned)(hq & 0xFF)) << (q * 8);
        }
        int brow = nf * 16 + l15;
        *(unsigned*)(hb8n + brow * H8STR + colv) = pk;
        if (!last)
          __hip_atomic_store(xob + brow * 64 + wv * 4 + l4, pk,
                             __ATOMIC_RELAXED, __HIP_MEMORY_SCOPE_AGENT);
      }

      // stage x(t+1) before the end-of-step barrier
      if (l == NL - 1 && t < S_LEN - 1){
        float xv = xvalid ? x[xbase + (size_t)(t + 1) * IN_D] : 0.f;
        xpack[(t + 1) & 1][tid] = f2bf(xv);
      }

      if (!last){
        asm volatile("s_waitcnt vmcnt(0)" ::: "memory");   // mailbox stores drained
        __syncthreads();
        if (tid == 0)
          __hip_atomic_store(&flags[bid], s + 1, __ATOMIC_RELAXED, __HIP_MEMORY_SCOPE_AGENT);
      }
      cur ^= 1;
    }
  }
#undef DO_KK

  // epilogue: lane holds 4 consecutive out-cols per batch-frag -> dwordx4 stores
#pragma unroll
  for (int nf = 0; nf < 2; ++nf){
    f32x4 v = { hreg[nf][0], hreg[nf][1], hreg[nf][2], hreg[nf][3] };
    int brow = nf * 16 + l15;
    *(f32x4*)&out[((size_t)(b0 + brow)) * 512 + colv] = v;
  }

  if (flags[bid] == -2) out[0] = (float)pad[tid];   // pad liveness (never true)
}

extern "C" void kernel_launch(void* const* d_in, const int* in_sizes, int n_in,
                              void* d_out, int out_size, void* d_ws, size_t ws_size,
                              hipStream_t stream){
  const float* x   = (const float*)d_in[0];
  const float* Wih = (const float*)d_in[1];
  const float* Whh = (const float*)d_in[2];
  const float* bih = (const float*)d_in[3];
  const float* bhh = (const float*)d_in[4];

  unsigned char* ws = (unsigned char*)d_ws;
  unsigned char*  Wp8  = (unsigned char*)(ws + OFF_WI8);
  unsigned short* Wip  = (unsigned short*)(ws + OFF_WIH);
  float*          sw   = (float*)(ws + OFF_SW);
  float*          swi  = (float*)(ws + OFF_SWI);
  int*            flg  = (int*)(ws + OFF_FLAG);
  unsigned int*   xchg = (unsigned int*)(ws + OFF_XCHG);

  hipMemsetAsync(flg, 0, 256 * sizeof(int), stream);
  prep_scale<<<1152, 256, 0, stream>>>(Whh, sw, swi);
  prep_wi8  <<< 576, 256, 0, stream>>>(Whh, swi, Wp8);
  prep_wih  <<<  72, 256, 0, stream>>>(Wih, Wip);
  gru_main  <<< 256, 1024, 0, stream>>>(x, Wp8, Wip, bih, bhh, sw, (float*)d_out, flg, xchg);
}